// Round 11
// baseline (3116.081 us; speedup 1.0000x reference)
//
#include <hip/hip_runtime.h>

#define Tc 100
#define Hc 512
#define Lc 3
#define H3c 1536
#define HLAY (Hc*Hc)            // elems per layer slice of an hb parity slot
#define HSLOT (Lc*HLAY)         // elems per parity slot

typedef short bf16x8 __attribute__((ext_vector_type(8)));
typedef float f32x4 __attribute__((ext_vector_type(4)));

__device__ __forceinline__ unsigned short f2bf(float f) {
  unsigned int u = __float_as_uint(f);
  u += 0x7FFFu + ((u >> 16) & 1u);   // round-to-nearest-even
  return (unsigned short)(u >> 16);
}

__global__ __launch_bounds__(256) void conv_bf16(const float* __restrict__ src,
                                                 unsigned short* __restrict__ dst,
                                                 int n4) {
  int i = blockIdx.x * 256 + threadIdx.x;
  if (i >= n4) return;
  f32x4 v = *(const f32x4*)(src + (size_t)i * 4);
  ushort4 o;
  o.x = f2bf(v[0]); o.y = f2bf(v[1]); o.z = f2bf(v[2]); o.w = f2bf(v[3]);
  *(ushort4*)(dst + (size_t)i * 4) = o;
}

// Lane-parallel group wait on 32 monotonic per-producer counters (store-
// published, never RMW'd). sc0sc1 polls read the coherence point. Self-drains.
__device__ __forceinline__ void waitg(const int* slots, int tgt, int lane) {
  const int* p = slots + (lane & 31);
  int it = 0;
  for (;;) {
    int v;
    asm volatile("global_load_dword %0, %1, off sc0 sc1\n\ts_waitcnt vmcnt(0)"
                 : "=v"(v) : "v"(p) : "memory");
    if (__all(v >= tgt)) break;
    __builtin_amdgcn_s_sleep(1);
    if (++it > 4000000) break;      // deadlock bug -> fast fail, not hang
  }
}

#define LOADN(dst, ptr) \
  asm volatile("global_load_dwordx4 %0, %1, off" : "=v"(dst) : "v"(ptr))
#define STORE_H2(ptr, v32) \
  asm volatile("global_store_short %0, %1, off sc0 sc1" :: "v"(ptr), "v"(v32))
#define STORE_D(ptr, v32) \
  asm volatile("global_store_dword %0, %1, off sc0 sc1" :: "v"(ptr), "v"(v32))
#define WAITV(n) do { asm volatile("s_waitcnt vmcnt(" #n ")" ::: "memory"); \
                      __builtin_amdgcn_sched_barrier(0); } while (0)
#define MM(a, b, c) c = __builtin_amdgcn_mfma_f32_16x16x32_bf16(a, b, c, 0, 0, 0)

// Persistent dataflow GRU — round-8 passing skeleton (row-major h ring,
// counted-vmcnt K-loop, RMW-free done[] flags, scattered STORE_H2 epilogue)
// with the READ PATH changed:
//  - H/A K-loop loads are NORMAL cached loads (L2-shared among the 16-32
//    same-slice blocks) instead of L2-bypassing sc loads (98 MB/stage of
//    unshared coherence-point transactions -> the dominant stage cost).
//  - ONE agent-acquire (buffer_inv) per stage, after the flag waits and
//    before any H/A load. Producer sc stores are at L3 before the flag is
//    visible; flag logic serializes slot readers vs slot writers, so cached
//    reads are safe. (inv + dirty-y coexistence validated in rounds 2-3.)
//  - Packed XCD map f=(bid&7)*24+(bid>>3): each (l,rb) group spans only 2
//    XCDs so its h-slice lines are shared in L2 by 16 blocks.
__global__ __launch_bounds__(256, 1) void gru_persist10(
    const float* __restrict__ x,     // [B,T,A,H] f32 (fallback)
    const short* __restrict__ xb,    // [B,T,A,H] bf16 or nullptr
    const short* __restrict__ wbih,  // [L,3H,H] bf16
    const short* __restrict__ wbhh,  // [L,3H,H] bf16
    const float* __restrict__ bih,   // [L,3H]
    const float* __restrict__ bhh,   // [L,3H]
    short* hb,                       // [2][L][512][512] bf16 parity ring
    const int* __restrict__ valid,   // [B,T,A] int32
    float* __restrict__ y,           // [B,T,A,H] f32
    int* done) {                     // [6][32] monotonic counters
  __shared__ char wlds[98304];

  const int bid = blockIdx.x;
  const int f = (bid & 7) * 24 + (bid >> 3);   // pack each group onto <=2 XCDs
  const int gi = f >> 5;             // group = l*2+rb, 0..5
  const int cb = f & 31;             // 0..31
  const int l = gi >> 1;
  const int rb = gi & 1;
  const int c0 = cb * 16;
  const int R0 = rb * 256;

  const int tid = threadIdx.x;
  const int w = tid >> 6;
  const int lane = tid & 63;
  const int lrow = lane & 15;
  const int kgrp = lane >> 4;

  const short* wih_l = wbih + (size_t)l * H3c * Hc;
  const short* whh_l = wbhh + (size_t)l * H3c * Hc;

  // ---- one-time LDS weight fill: frag j = m*16+ks, lane-linear ----
#pragma unroll
  for (int j4 = 0; j4 < 24; ++j4) {
    int j = j4 * 4 + w;
    int m = j >> 4, ks = j & 15;
    int g = (m < 3) ? m : m - 3;
    int n = g * Hc + c0 + lrow;
    const short* src = ((m < 3) ? wih_l : whh_l) + (size_t)n * Hc + ks * 32 + kgrp * 8;
    *(bf16x8*)(wlds + (size_t)j * 1024 + lane * 16) = *(const bf16x8*)src;
  }
  __syncthreads();

  const char* wl = wlds + (lane << 4);

  const float* bihl = bih + l * H3c;
  const float* bhhl = bhh + l * H3c;
  const int c = c0 + lrow;
  const float bi0 = bihl[c], bi1 = bihl[Hc + c], bi2 = bihl[2 * Hc + c];
  const float bh0 = bhhl[c], bh1 = bhhl[Hc + c], bh2 = bhhl[2 * Hc + c];

  f32x4 hreg[4];
#pragma unroll
  for (int rf = 0; rf < 4; ++rf) hreg[rf] = f32x4{0.f, 0.f, 0.f, 0.f};

  WAITV(0);                          // setup loads drained before counted regions

  for (int t = 0; t < Tc; ++t) {
    // parallel waits on 3 waves (coherence-point polls, no RMW anywhere)
    if (w == 0 && l > 0)           waitg(done + ((l - 1) * 2 + rb) * 32, t + 1, lane);
    if (w == 1 && t > 0)           waitg(done + gi * 32, t, lane);
    if (w == 2 && l < 2 && t >= 2) waitg(done + ((l + 1) * 2 + rb) * 32, t - 1, lane);
    __syncthreads();
    // per-stage acquire: vmcnt/lgkm drain + buffer_inv so the following NORMAL
    // loads can't hit stale L1/L2 h lines. Executed by all waves (L1 is
    // per-CU, one block per CU). Leaves vmcnt=0.
    (void)__hip_atomic_load(done + gi * 32 + cb, __ATOMIC_ACQUIRE,
                            __HIP_MEMORY_SCOPE_AGENT);
    __builtin_amdgcn_sched_barrier(0);

    const int par = t & 1;
    const short* hprev = hb + (size_t)(1 - par) * HSLOT + (size_t)l * HLAY;

    const short* pH[4];
    const short* pA[4] = {nullptr, nullptr, nullptr, nullptr};
    const float* pXf[4] = {x, x, x, x};
#pragma unroll
    for (int rf = 0; rf < 4; ++rf) {
      int row = R0 + w * 64 + rf * 16 + lrow;
      pH[rf] = hprev + (size_t)row * Hc;
      if (l > 0) {
        pA[rf] = hb + (size_t)par * HSLOT + (size_t)(l - 1) * HLAY + (size_t)row * Hc;
      } else {
        int bb = row >> 6, aa = row & 63;
        size_t rofs = ((size_t)bb * Tc + t) * 64 + aa;
        if (xb) pA[rf] = xb + rofs * Hc;
        pXf[rf] = x + rofs * Hc;
      }
    }

    f32x4 acc[6][4];
#pragma unroll
    for (int m = 0; m < 6; ++m)
#pragma unroll
      for (int rf = 0; rf < 4; ++rf) acc[m][rf] = f32x4{0.f, 0.f, 0.f, 0.f};

#define AI_ISSUE_N(I_, rf, k2, addr) LOADN(I_[rf][k2], addr)
#define AI_ISSUE_X(I_, rf, k2, addr)
#define AI_GET_REG(dst, I_, rf, k2, ks) dst = I_[rf][k2]
#define AI_GET_F32(dst, I_, rf, k2, ks)                                            \
      {                                                                            \
        const float* _px = pXf[rf] + (ks) * 32 + (kgrp << 3);                      \
        f32x4 v0 = *(const f32x4*)_px;                                             \
        f32x4 v1 = *(const f32x4*)(_px + 4);                                       \
        bf16x8 t_;                                                                 \
        _Pragma("unroll") for (int e = 0; e < 4; ++e) {                            \
          t_[e] = (short)f2bf(v0[e]); t_[4 + e] = (short)f2bf(v1[e]);              \
        }                                                                          \
        dst = t_;                                                                  \
      }

#define ISSUE(H_, I_, g2, AI_ISS)                                                  \
      { _Pragma("unroll") for (int rf = 0; rf < 4; ++rf)                           \
          _Pragma("unroll") for (int k2 = 0; k2 < 2; ++k2) {                       \
            const int ke = ((g2) * 2 + k2) * 32 + (kgrp << 3);                     \
            LOADN(H_[rf][k2], pH[rf] + ke);                                        \
            AI_ISS(I_, rf, k2, pA[rf] + ke);                                       \
          } }

#define CONSUME(H_, I_, g2, AI_GET)                                                \
      { _Pragma("unroll") for (int k2 = 0; k2 < 2; ++k2) {                         \
          const int ks = (g2) * 2 + k2;                                            \
          bf16x8 Bg0 = *(const bf16x8*)(wl + ((0 * 16 + ks) << 10));               \
          bf16x8 Bg1 = *(const bf16x8*)(wl + ((1 * 16 + ks) << 10));               \
          bf16x8 Bg2 = *(const bf16x8*)(wl + ((2 * 16 + ks) << 10));               \
          bf16x8 Bg3 = *(const bf16x8*)(wl + ((3 * 16 + ks) << 10));               \
          bf16x8 Bg4 = *(const bf16x8*)(wl + ((4 * 16 + ks) << 10));               \
          bf16x8 Bg5 = *(const bf16x8*)(wl + ((5 * 16 + ks) << 10));               \
          _Pragma("unroll") for (int rf = 0; rf < 4; ++rf) {                       \
            bf16x8 Ai_; AI_GET(Ai_, I_, rf, k2, ks);                               \
            MM(Ai_, Bg0, acc[0][rf]);                                              \
            MM(Ai_, Bg1, acc[1][rf]);                                              \
            MM(Ai_, Bg2, acc[2][rf]);                                              \
            MM(H_[rf][k2], Bg3, acc[3][rf]);                                       \
            MM(H_[rf][k2], Bg4, acc[4][rf]);                                       \
            MM(H_[rf][k2], Bg5, acc[5][rf]);                                       \
          } } }

#define KLOOP(AI_ISS, AI_GET, WMID)                                                \
      {                                                                            \
        bf16x8 gHa[4][2], gIa[4][2], gHb[4][2], gIb[4][2];                         \
        ISSUE(gHa, gIa, 0, AI_ISS);                                                \
        _Pragma("unroll") for (int g2 = 0; g2 < 8; g2 += 2) {                      \
          ISSUE(gHb, gIb, g2 + 1, AI_ISS);                                         \
          WAITV(WMID);                                                             \
          CONSUME(gHa, gIa, g2, AI_GET);                                           \
          if (g2 + 2 < 8) {                                                        \
            ISSUE(gHa, gIa, g2 + 2, AI_ISS);                                       \
            WAITV(WMID);                                                           \
          } else {                                                                 \
            WAITV(0);                                                              \
          }                                                                        \
          CONSUME(gHb, gIb, g2 + 1, AI_GET);                                       \
        }                                                                          \
      }

    __builtin_amdgcn_sched_barrier(0);
    if (l > 0 || xb) {
      KLOOP(AI_ISSUE_N, AI_GET_REG, 16)
    } else {                         // fallback: single-buffered, full drains
      bf16x8 gHa[4][2], gIa[4][2];
#pragma unroll
      for (int g2 = 0; g2 < 8; ++g2) {
        ISSUE(gHa, gIa, g2, AI_ISSUE_X);
        WAITV(0);
        CONSUME(gHa, gIa, g2, AI_GET_F32);
      }
    }
    __builtin_amdgcn_sched_barrier(0);

    // epilogue (round-8 proven form): C/D map col=lane&15, row=(lane>>4)*4+reg
    short* hout = hb + (size_t)par * HSLOT + (size_t)l * HLAY;
#pragma unroll
    for (int rf = 0; rf < 4; ++rf) {
#pragma unroll
      for (int rr = 0; rr < 4; ++rr) {
        int rowg = R0 + w * 64 + rf * 16 + kgrp * 4 + rr;
        int bb = rowg >> 6, aa = rowg & 63;
        size_t vofs = ((size_t)bb * Tc + t) * 64 + aa;
        int vld = valid[vofs];
        float ir = acc[0][rf][rr] + bi0;
        float iz = acc[1][rf][rr] + bi1;
        float in_ = acc[2][rf][rr] + bi2;
        float hr = acc[3][rf][rr] + bh0;
        float hz = acc[4][rf][rr] + bh1;
        float hn = acc[5][rf][rr] + bh2;
        float rg = 1.0f / (1.0f + __expf(-(ir + hr)));
        float zg = 1.0f / (1.0f + __expf(-(iz + hz)));
        float ng = tanhf(in_ + rg * hn);
        float hnew = (1.0f - zg) * ng + zg * hreg[rf][rr];
        if (!vld) hnew = 0.0f;
        hreg[rf][rr] = hnew;
        int hv = (int)f2bf(hnew);
        STORE_H2(hout + (size_t)rowg * Hc + c, hv);
        if (l == 2) y[vofs * Hc + c] = hnew;
      }
    }

    asm volatile("s_waitcnt vmcnt(0)" ::: "memory");   // sc stores + y drained
    __syncthreads();                                   // all waves' stores done
    if (tid == 0) {                  // publish: single sc STORE, no RMW
      int v = t + 1;
      STORE_D(done + gi * 32 + cb, v);
    }
    WAITV(0);   // drain publish store: vmcnt clean for next counted region
  }
}

extern "C" void kernel_launch(void* const* d_in, const int* in_sizes, int n_in,
                              void* d_out, int out_size, void* d_ws, size_t ws_size,
                              hipStream_t stream) {
  const float* x = (const float*)d_in[0];
  const int* valid = (const int*)d_in[1];
  const float* w_ih = (const float*)d_in[2];
  const float* w_hh = (const float*)d_in[3];
  const float* b_ih = (const float*)d_in[4];
  const float* b_hh = (const float*)d_in[5];
  float* y = (float*)d_out;

  char* ws = (char*)d_ws;
  const size_t welems = (size_t)Lc * H3c * Hc;            // 2,359,296
  unsigned short* wbih = (unsigned short*)ws;
  unsigned short* wbhh = (unsigned short*)(ws + welems * 2);
  short* hb = (short*)(ws + welems * 4);                  // 3.0 MB ring
  const size_t hb_bytes = (size_t)2 * HSLOT * 2;
  int* done = (int*)(ws + welems * 4 + hb_bytes);         // [6][32] = 768 B
  const size_t flags_bytes = 4800;
  const size_t xb_off = welems * 4 + hb_bytes + flags_bytes;  // 16B aligned
  const size_t xelems = (size_t)8 * Tc * 64 * Hc;         // 26,214,400
  const bool big = ws_size >= xb_off + xelems * 2;
  unsigned short* xbf = big ? (unsigned short*)(ws + xb_off) : nullptr;

  int n4w = (int)(welems / 4);
  conv_bf16<<<(n4w + 255) / 256, 256, 0, stream>>>(w_ih, wbih, n4w);
  conv_bf16<<<(n4w + 255) / 256, 256, 0, stream>>>(w_hh, wbhh, n4w);
  if (big) {
    int n4x = (int)(xelems / 4);
    conv_bf16<<<(n4x + 255) / 256, 256, 0, stream>>>(x, xbf, n4x);
  }
  (void)hipMemsetAsync(hb, 0, hb_bytes + flags_bytes, stream);

  gru_persist10<<<192, 256, 0, stream>>>(x, (const short*)xbf,
                                         (const short*)wbih, (const short*)wbhh,
                                         b_ih, b_hh, hb, valid, y, done);
}